// Round 1
// baseline (1726.893 us; speedup 1.0000x reference)
//
#include <hip/hip_runtime.h>
#include <hip/hip_bf16.h>

typedef float f32x4 __attribute__((ext_vector_type(4)));
typedef short bf16x8 __attribute__((ext_vector_type(8)));

constexpr int BM = 64, BN = 64, BK = 32;
constexpr int LDT = BK + 8;  // padded LDS row stride (bf16): 40 elems = 80 B, keeps 16B alignment

// C = A @ B (+bias), A fp32 [M,K] row-major (lda), B fp32 (ldb):
//   B_TRANS=false: B is [K,N] row-major; true: B source is [N,K] row-major (i.e. compute A@B^T).
// SPLIT: decompose A,B into bf16 hi+lo, 3 MFMAs (near-fp32 product accuracy).
// MODE: 0 = plain; 1 = scores (skip tiles with ct>rt, causal); 2 = PV (K-loop bounded by row tile).
template<bool SPLIT, bool B_TRANS, int MODE>
__global__ __launch_bounds__(256)
void gemm_kernel(const float* __restrict__ A, long sA, int lda,
                 const float* __restrict__ B, long sB, int ldb,
                 float* __restrict__ C, long sC, int ldc,
                 int K, const float* __restrict__ bias)
{
    const int rt = blockIdx.y, ct = blockIdx.x, bz = blockIdx.z;
    if (MODE == 1 && ct > rt) return;
    A += (long)bz * sA; B += (long)bz * sB; C += (long)bz * sC;
    const int row0 = rt * BM, col0 = ct * BN;
    const int k_end = (MODE == 2) ? min(K, (rt + 1) * BM) : K;

    __shared__ __hip_bfloat16 Ah[BM][LDT];
    __shared__ __hip_bfloat16 Bh[BN][LDT];
    __shared__ __hip_bfloat16 Al[SPLIT ? BM : 1][SPLIT ? LDT : 1];
    __shared__ __hip_bfloat16 Bl[SPLIT ? BN : 1][SPLIT ? LDT : 1];

    const int tid = threadIdx.x;
    const int lane = tid & 63, wave = tid >> 6;
    const int lane16 = lane & 15, quad = lane >> 4;
    const int wm = (wave >> 1) * 32, wn = (wave & 1) * 32;

    f32x4 acc[2][2] = {};

    for (int k0 = 0; k0 < k_end; k0 += BK) {
        __syncthreads();  // protect previous iteration's fragment reads
        {   // stage A tile (BM x BK), coalesced 32 lanes/row
            const int c = tid & 31, r0 = tid >> 5;
            for (int r = r0; r < BM; r += 8) {
                float v = A[(long)(row0 + r) * lda + (k0 + c)];
                __hip_bfloat16 h = __float2bfloat16(v);
                Ah[r][c] = h;
                if (SPLIT) Al[r][c] = __float2bfloat16(v - __bfloat162float(h));
            }
        }
        if (B_TRANS) {  // B source [N,K]: stage rows directly (already n-major)
            const int c = tid & 31, r0 = tid >> 5;
            for (int r = r0; r < BN; r += 8) {
                float v = B[(long)(col0 + r) * ldb + (k0 + c)];
                __hip_bfloat16 h = __float2bfloat16(v);
                Bh[r][c] = h;
                if (SPLIT) Bl[r][c] = __float2bfloat16(v - __bfloat162float(h));
            }
        } else {        // B source [K,N]: coalesced read over n, transposed LDS write
            const int n = tid & 63, kk0 = tid >> 6;
            for (int kk = kk0; kk < BK; kk += 4) {
                float v = B[(long)(k0 + kk) * ldb + (col0 + n)];
                __hip_bfloat16 h = __float2bfloat16(v);
                Bh[n][kk] = h;
                if (SPLIT) Bl[n][kk] = __float2bfloat16(v - __bfloat162float(h));
            }
        }
        __syncthreads();

        // fragments: A[m][k]: m=lane16, k=quad*8+j ; B[k][n]: n=lane16, k=quad*8+j
        bf16x8 ah[2], bh[2];
        for (int i = 0; i < 2; ++i)
            ah[i] = *reinterpret_cast<const bf16x8*>(&Ah[wm + i * 16 + lane16][quad * 8]);
        for (int j = 0; j < 2; ++j)
            bh[j] = *reinterpret_cast<const bf16x8*>(&Bh[wn + j * 16 + lane16][quad * 8]);
        if (SPLIT) {
            bf16x8 al[2], bl[2];
            for (int i = 0; i < 2; ++i)
                al[i] = *reinterpret_cast<const bf16x8*>(&Al[wm + i * 16 + lane16][quad * 8]);
            for (int j = 0; j < 2; ++j)
                bl[j] = *reinterpret_cast<const bf16x8*>(&Bl[wn + j * 16 + lane16][quad * 8]);
            for (int i = 0; i < 2; ++i)
                for (int j = 0; j < 2; ++j) {
                    acc[i][j] = __builtin_amdgcn_mfma_f32_16x16x32_bf16(ah[i], bh[j], acc[i][j], 0, 0, 0);
                    acc[i][j] = __builtin_amdgcn_mfma_f32_16x16x32_bf16(ah[i], bl[j], acc[i][j], 0, 0, 0);
                    acc[i][j] = __builtin_amdgcn_mfma_f32_16x16x32_bf16(al[i], bh[j], acc[i][j], 0, 0, 0);
                }
        } else {
            for (int i = 0; i < 2; ++i)
                for (int j = 0; j < 2; ++j)
                    acc[i][j] = __builtin_amdgcn_mfma_f32_16x16x32_bf16(ah[i], bh[j], acc[i][j], 0, 0, 0);
        }
    }

    // epilogue: C/D layout col=lane16, row=quad*4+r
    for (int j = 0; j < 2; ++j) {
        const int col = col0 + wn + j * 16 + lane16;
        const float bval = bias ? bias[col] : 0.0f;
        for (int i = 0; i < 2; ++i) {
            const int rbase = row0 + wm + i * 16 + quad * 4;
            for (int r = 0; r < 4; ++r)
                C[(long)(rbase + r) * ldc + col] = acc[i][j][r] + bval;
        }
    }
}

// In-place causal softmax over row r of S [B, seq, seq]; reads cols<=r, writes all seq cols
// (zeros beyond r so the PV GEMM can consume full tiles).
__global__ __launch_bounds__(256)
void softmax_kernel(float* __restrict__ S, int seq)
{
    const int r = blockIdx.x, b = blockIdx.y;
    float* row = S + ((long)b * seq + r) * seq;
    const int tid = threadIdx.x;
    float vals[8];
    float lmax = -3.0e38f;
    for (int i = 0; i < 8; ++i) {
        int c = i * 256 + tid;
        float v = (c <= r) ? row[c] : -3.0e38f;
        vals[i] = v;
        lmax = fmaxf(lmax, v);
    }
    __shared__ float red[256];
    red[tid] = lmax; __syncthreads();
    for (int s = 128; s > 0; s >>= 1) {
        if (tid < s) red[tid] = fmaxf(red[tid], red[tid + s]);
        __syncthreads();
    }
    const float m = red[0];
    __syncthreads();
    float lsum = 0.0f;
    for (int i = 0; i < 8; ++i) {
        int c = i * 256 + tid;
        float e = (c <= r) ? expf(vals[i] - m) : 0.0f;
        vals[i] = e;
        lsum += e;
    }
    red[tid] = lsum; __syncthreads();
    for (int s = 128; s > 0; s >>= 1) {
        if (tid < s) red[tid] += red[tid + s];
        __syncthreads();
    }
    const float inv = 1.0f / red[0];
    for (int i = 0; i < 8; ++i) {
        int c = i * 256 + tid;
        row[c] = vals[i] * inv;
    }
}

extern "C" void kernel_launch(void* const* d_in, const int* in_sizes, int n_in,
                              void* d_out, int out_size, void* d_ws, size_t ws_size,
                              hipStream_t stream)
{
    constexpr int B = 4, S = 2048, D = 1024;
    const float* x  = (const float*)d_in[0];
    const float* Wq = (const float*)d_in[1];
    const float* bq = (const float*)d_in[2];
    const float* Wk = (const float*)d_in[3];
    const float* bk = (const float*)d_in[4];
    const float* Wv = (const float*)d_in[5];
    const float* bv = (const float*)d_in[6];
    float* out = (float*)d_out;

    // workspace layout (fp32): Q | K | V | Scores(->P in place)  = 3*32MB + 64MB = 168MB
    float* Q  = (float*)d_ws;
    float* Km = Q  + (long)B * S * D;
    float* V  = Km + (long)B * S * D;
    float* Sc = V  + (long)B * S * D;

    const int M = B * S;  // 8192, x flattened [M, D]
    dim3 blk(256);

    // projections: Q,K with split-bf16 (feeds softmax scores), V single-bf16
    gemm_kernel<true,  false, 0><<<dim3(D / BN, M / BM, 1), blk, 0, stream>>>(
        x, 0, D, Wq, 0, D, Q, 0, D, D, bq);
    gemm_kernel<true,  false, 0><<<dim3(D / BN, M / BM, 1), blk, 0, stream>>>(
        x, 0, D, Wk, 0, D, Km, 0, D, D, bk);
    gemm_kernel<false, false, 0><<<dim3(D / BN, M / BM, 1), blk, 0, stream>>>(
        x, 0, D, Wv, 0, D, V, 0, D, D, bv);

    // scores = Q @ K^T per batch (split-bf16, lower-triangular tiles only)
    gemm_kernel<true,  true,  1><<<dim3(S / BN, S / BM, B), blk, 0, stream>>>(
        Q, (long)S * D, D, Km, (long)S * D, D, Sc, (long)S * S, S, D, nullptr);

    // causal softmax in place (writes zeros above diagonal)
    softmax_kernel<<<dim3(S, B), blk, 0, stream>>>(Sc, S);

    // out = P @ V per batch (K-loop bounded at diagonal tile)
    gemm_kernel<false, false, 2><<<dim3(D / BN, S / BM, B), blk, 0, stream>>>(
        Sc, (long)S * S, S, V, (long)S * D, D, out, (long)S * D, D, S, nullptr);
}

// Round 2
// 440.193 us; speedup vs baseline: 3.9230x; 3.9230x over previous
//
#include <hip/hip_runtime.h>
#include <hip/hip_bf16.h>

typedef float f32x4 __attribute__((ext_vector_type(4)));
typedef short bf16x8 __attribute__((ext_vector_type(8)));
typedef unsigned short u16x4 __attribute__((ext_vector_type(4)));

__device__ inline unsigned short f2bf(float v) {
    __hip_bfloat16 h = __float2bfloat16(v);
    return *reinterpret_cast<unsigned short*>(&h);
}
__device__ inline float bf2f(unsigned short u) {
    __hip_bfloat16 h;
    *reinterpret_cast<unsigned short*>(&h) = u;
    return __bfloat162float(h);
}

// ---------------------------------------------------------------------------
// convert_split: fp32 -> bf16 hi + lo (elementwise), float4-vectorized
// ---------------------------------------------------------------------------
__global__ __launch_bounds__(256)
void convert_split(const float* __restrict__ X, unsigned short* __restrict__ H,
                   unsigned short* __restrict__ L, long n4)
{
    long i = (long)blockIdx.x * 256 + threadIdx.x;
    if (i >= n4) return;
    f32x4 v = ((const f32x4*)X)[i];
    u16x4 h, l;
#pragma unroll
    for (int k = 0; k < 4; ++k) {
        h[k] = f2bf(v[k]);
        l[k] = f2bf(v[k] - bf2f(h[k]));
    }
    ((u16x4*)H)[i] = h;
    ((u16x4*)L)[i] = l;
}

// ---------------------------------------------------------------------------
// transpose_w: W [D][D] fp32 row-major -> Wt [n][k] bf16 hi (+lo if SPL)
// ---------------------------------------------------------------------------
template<bool SPL>
__global__ __launch_bounds__(256)
void transpose_w(const float* __restrict__ W, unsigned short* __restrict__ Th,
                 unsigned short* __restrict__ Tl, int D)
{
    __shared__ float t[32][33];
    const int tid = threadIdx.x;
    const int bx = blockIdx.x * 32, by = blockIdx.y * 32;
    const int c = tid & 31, r0 = tid >> 5;
#pragma unroll
    for (int r = r0; r < 32; r += 8)
        t[r][c] = W[(long)(by + r) * D + bx + c];
    __syncthreads();
#pragma unroll
    for (int r = r0; r < 32; r += 8) {
        float v = t[c][r];                       // = W[by+c][bx+r]
        unsigned short h = f2bf(v);
        Th[(long)(bx + r) * D + by + c] = h;     // Wt[n=bx+r][k=by+c]
        if (SPL) Tl[(long)(bx + r) * D + by + c] = f2bf(v - bf2f(h));
    }
}

// ---------------------------------------------------------------------------
// gemm2: C = A @ B^T_layout (+bias). A bf16 [M][K] row-major (hi, + lo if SPLIT),
// B bf16 [N][K] row-major (hi, + lo). 128x128 tile, BK=32, 16x16x32 MFMA,
// global_load_lds width-16 staging.
// MODE: 0 plain; 1 causal tile skip (ct>rt); 2 K-loop bounded at (rt+1)*128.
// OUT:  0 fp32 Cf[ldc]; 1 split bf16 Ch/Cl[ldc]; 2 transposed bf16 Ch[b][col][s].
// ---------------------------------------------------------------------------
constexpr int TM = 128, TN = 128, TK = 32;

template<bool SPLIT, int MODE, int OUT>
__global__ __launch_bounds__(256)
void gemm2(const unsigned short* __restrict__ Ah, const unsigned short* __restrict__ Al,
           long sA, int lda,
           const unsigned short* __restrict__ Bh, const unsigned short* __restrict__ Bl,
           long sB, int ldb,
           float* __restrict__ Cf, unsigned short* __restrict__ Ch, unsigned short* __restrict__ Cl,
           long sC, int ldc, int K, const float* __restrict__ bias, int batchS)
{
    const int rt = blockIdx.y, ct = blockIdx.x, bz = blockIdx.z;
    if (MODE == 1 && ct > rt) return;

    const unsigned short* gAh = Ah + (long)bz * sA;
    const unsigned short* gAl = SPLIT ? Al + (long)bz * sA : nullptr;
    const unsigned short* gBh = Bh + (long)bz * sB;
    const unsigned short* gBl = SPLIT ? Bl + (long)bz * sB : nullptr;

    const int row0 = rt * TM, col0 = ct * TN;
    const int k_end = (MODE == 2) ? min(K, (rt + 1) * TM) : K;

    __shared__ unsigned short sAh[TM * TK];               // 8 KB, rows of 64 B, unpadded
    __shared__ unsigned short sBh[TN * TK];
    __shared__ unsigned short sAl[SPLIT ? TM * TK : 8];
    __shared__ unsigned short sBl[SPLIT ? TN * TK : 8];

    const int tid = threadIdx.x;
    const int lane = tid & 63, wave = tid >> 6;
    const int l16 = lane & 15, quad = lane >> 4;
    const int wm = (wave >> 1) * 64, wn = (wave & 1) * 64;

    f32x4 acc[4][4] = {};

    for (int k0 = 0; k0 < k_end; k0 += TK) {
        // stage 128x32 bf16 tiles: 2 rounds of 256 lanes x 16 B each
#pragma unroll
        for (int rnd = 0; rnd < 2; ++rnd) {
            const int row = rnd * 64 + (tid >> 2);
            const long gofs = (long)row * lda + k0 + (tid & 3) * 8;
            const int lofs = rnd * 2048 + tid * 8;
            __builtin_amdgcn_global_load_lds(
                (const __attribute__((address_space(1))) void*)(gAh + (long)(row0) * lda + gofs),
                (__attribute__((address_space(3))) void*)(sAh + lofs), 16, 0, 0);
            __builtin_amdgcn_global_load_lds(
                (const __attribute__((address_space(1))) void*)(gBh + (long)(col0) * ldb + (long)row * ldb + k0 + (tid & 3) * 8),
                (__attribute__((address_space(3))) void*)(sBh + lofs), 16, 0, 0);
            if (SPLIT) {
                __builtin_amdgcn_global_load_lds(
                    (const __attribute__((address_space(1))) void*)(gAl + (long)(row0) * lda + gofs),
                    (__attribute__((address_space(3))) void*)(sAl + lofs), 16, 0, 0);
                __builtin_amdgcn_global_load_lds(
                    (const __attribute__((address_space(1))) void*)(gBl + (long)(col0) * ldb + (long)row * ldb + k0 + (tid & 3) * 8),
                    (__attribute__((address_space(3))) void*)(sBl + lofs), 16, 0, 0);
            }
        }
        __syncthreads();

        bf16x8 a_h[4], b_h[4];
#pragma unroll
        for (int i = 0; i < 4; ++i)
            a_h[i] = *(const bf16x8*)&sAh[(wm + i * 16 + l16) * TK + (quad << 3)];
#pragma unroll
        for (int j = 0; j < 4; ++j)
            b_h[j] = *(const bf16x8*)&sBh[(wn + j * 16 + l16) * TK + (quad << 3)];

        if (SPLIT) {
            bf16x8 a_l[4], b_l[4];
#pragma unroll
            for (int i = 0; i < 4; ++i)
                a_l[i] = *(const bf16x8*)&sAl[(wm + i * 16 + l16) * TK + (quad << 3)];
#pragma unroll
            for (int j = 0; j < 4; ++j)
                b_l[j] = *(const bf16x8*)&sBl[(wn + j * 16 + l16) * TK + (quad << 3)];
#pragma unroll
            for (int i = 0; i < 4; ++i)
#pragma unroll
                for (int j = 0; j < 4; ++j) {
                    acc[i][j] = __builtin_amdgcn_mfma_f32_16x16x32_bf16(a_h[i], b_h[j], acc[i][j], 0, 0, 0);
                    acc[i][j] = __builtin_amdgcn_mfma_f32_16x16x32_bf16(a_h[i], b_l[j], acc[i][j], 0, 0, 0);
                    acc[i][j] = __builtin_amdgcn_mfma_f32_16x16x32_bf16(a_l[i], b_h[j], acc[i][j], 0, 0, 0);
                }
        } else {
#pragma unroll
            for (int i = 0; i < 4; ++i)
#pragma unroll
                for (int j = 0; j < 4; ++j)
                    acc[i][j] = __builtin_amdgcn_mfma_f32_16x16x32_bf16(a_h[i], b_h[j], acc[i][j], 0, 0, 0);
        }
        __syncthreads();
    }

    // epilogue; C/D layout: col = l16, row = quad*4 + r
    float* cf = (OUT == 0) ? Cf + (long)bz * sC : nullptr;
    unsigned short* ch = (OUT == 1) ? Ch + (long)bz * sC : Ch;
    unsigned short* cl = (OUT == 1) ? Cl + (long)bz * sC : nullptr;
    const int bb = (OUT == 2) ? row0 / batchS : 0;        // tiles never cross batches
    const int sbase = row0 - bb * batchS;

#pragma unroll
    for (int j = 0; j < 4; ++j) {
        const int col = col0 + wn + j * 16 + l16;
        const float bval = bias ? bias[col] : 0.0f;
#pragma unroll
        for (int i = 0; i < 4; ++i) {
            const int rb = wm + i * 16 + quad * 4;
#pragma unroll
            for (int r = 0; r < 4; ++r) {
                float v = acc[i][j][r] + bval;
                if (OUT == 0) {
                    cf[(long)(row0 + rb + r) * ldc + col] = v;
                } else if (OUT == 1) {
                    unsigned short h = f2bf(v);
                    ch[(long)(row0 + rb + r) * ldc + col] = h;
                    cl[(long)(row0 + rb + r) * ldc + col] = f2bf(v - bf2f(h));
                } else {
                    ch[(long)bb * sC + (long)col * batchS + (sbase + rb + r)] = f2bf(v);
                }
            }
        }
    }
}

// ---------------------------------------------------------------------------
// softmax: causal, reads fp32 Sc row, writes bf16 P row (zeros above diagonal)
// ---------------------------------------------------------------------------
__global__ __launch_bounds__(256)
void softmax_kernel(const float* __restrict__ Sc, unsigned short* __restrict__ P, int seq)
{
    const int r = blockIdx.x, b = blockIdx.y;
    const float* row = Sc + ((long)b * seq + r) * seq;
    unsigned short* prow = P + ((long)b * seq + r) * seq;
    const int tid = threadIdx.x;

    float v[8];
    const f32x4* rp = (const f32x4*)row;
    f32x4 v0 = rp[tid * 2], v1 = rp[tid * 2 + 1];
    const int c0 = tid * 8;
    float lmax = -3.0e38f;
#pragma unroll
    for (int k = 0; k < 4; ++k) {
        v[k]     = (c0 + k     <= r) ? v0[k] : -3.0e38f;
        v[k + 4] = (c0 + k + 4 <= r) ? v1[k] : -3.0e38f;
    }
#pragma unroll
    for (int k = 0; k < 8; ++k) lmax = fmaxf(lmax, v[k]);

    __shared__ float red[256];
    red[tid] = lmax; __syncthreads();
    for (int s = 128; s > 0; s >>= 1) {
        if (tid < s) red[tid] = fmaxf(red[tid], red[tid + s]);
        __syncthreads();
    }
    const float m = red[0];
    __syncthreads();

    float lsum = 0.0f;
#pragma unroll
    for (int k = 0; k < 8; ++k) {
        float e = (v[k] > -1.0e38f) ? __expf(v[k] - m) : 0.0f;
        v[k] = e;
        lsum += e;
    }
    red[tid] = lsum; __syncthreads();
    for (int s = 128; s > 0; s >>= 1) {
        if (tid < s) red[tid] += red[tid + s];
        __syncthreads();
    }
    const float inv = 1.0f / red[0];

    u16x4 o0, o1;
#pragma unroll
    for (int k = 0; k < 4; ++k) {
        o0[k] = f2bf(v[k] * inv);
        o1[k] = f2bf(v[k + 4] * inv);
    }
    ((u16x4*)prow)[tid * 2]     = o0;
    ((u16x4*)prow)[tid * 2 + 1] = o1;
}

// ---------------------------------------------------------------------------
extern "C" void kernel_launch(void* const* d_in, const int* in_sizes, int n_in,
                              void* d_out, int out_size, void* d_ws, size_t ws_size,
                              hipStream_t stream)
{
    constexpr int B = 4, S = 2048, D = 1024;
    constexpr long MB = 1024 * 1024;
    const float* x  = (const float*)d_in[0];
    const float* Wq = (const float*)d_in[1];
    const float* bq = (const float*)d_in[2];
    const float* Wk = (const float*)d_in[3];
    const float* bk = (const float*)d_in[4];
    const float* Wv = (const float*)d_in[5];
    const float* bv = (const float*)d_in[6];
    float* out = (float*)d_out;

    // workspace layout (144 MB total; Sc overlaps dead x/W; P overlaps dead Q)
    char* ws = (char*)d_ws;
    unsigned short* x_hi  = (unsigned short*)(ws + 0);
    unsigned short* x_lo  = (unsigned short*)(ws + 16 * MB);
    unsigned short* Wqt_h = (unsigned short*)(ws + 32 * MB);
    unsigned short* Wqt_l = (unsigned short*)(ws + 34 * MB);
    unsigned short* Wkt_h = (unsigned short*)(ws + 36 * MB);
    unsigned short* Wkt_l = (unsigned short*)(ws + 38 * MB);
    unsigned short* Wvt_h = (unsigned short*)(ws + 40 * MB);
    float*          Sc    = (float*)(ws + 0);            // [B][S][S] fp32, after x/W dead
    unsigned short* Q_hi  = (unsigned short*)(ws + 64 * MB);
    unsigned short* Q_lo  = (unsigned short*)(ws + 80 * MB);
    unsigned short* K_hi  = (unsigned short*)(ws + 96 * MB);
    unsigned short* K_lo  = (unsigned short*)(ws + 112 * MB);
    unsigned short* Vt    = (unsigned short*)(ws + 128 * MB);  // [B][D][S] bf16
    unsigned short* P     = Q_hi;                              // [B][S][S] bf16, after Q dead

    const int M = B * S;  // 8192
    dim3 blk(256);

    // 1) convert x -> hi/lo bf16
    convert_split<<<(M * D / 4 + 255) / 256, blk, 0, stream>>>(x, x_hi, x_lo, (long)M * D / 4);
    // 2) transpose+convert weights -> [n][k] bf16
    dim3 tgrid(D / 32, D / 32);
    transpose_w<true ><<<tgrid, blk, 0, stream>>>(Wq, Wqt_h, Wqt_l, D);
    transpose_w<true ><<<tgrid, blk, 0, stream>>>(Wk, Wkt_h, Wkt_l, D);
    transpose_w<false><<<tgrid, blk, 0, stream>>>(Wv, Wvt_h, nullptr, D);

    // 3) projections
    gemm2<true, 0, 1><<<dim3(D / TN, M / TM, 1), blk, 0, stream>>>(
        x_hi, x_lo, 0, D, Wqt_h, Wqt_l, 0, D, nullptr, Q_hi, Q_lo, 0, D, D, bq, S);
    gemm2<true, 0, 1><<<dim3(D / TN, M / TM, 1), blk, 0, stream>>>(
        x_hi, x_lo, 0, D, Wkt_h, Wkt_l, 0, D, nullptr, K_hi, K_lo, 0, D, D, bk, S);
    gemm2<false, 0, 2><<<dim3(D / TN, M / TM, 1), blk, 0, stream>>>(
        x_hi, nullptr, 0, D, Wvt_h, nullptr, 0, D, nullptr, Vt, nullptr, (long)D * S, D, D, bv, S);

    // 4) scores = Q @ K^T (split, causal tiles only) -> fp32 Sc
    gemm2<true, 1, 0><<<dim3(S / TN, S / TM, B), blk, 0, stream>>>(
        Q_hi, Q_lo, (long)S * D, D, K_hi, K_lo, (long)S * D, D, Sc, nullptr, nullptr,
        (long)S * S, S, D, nullptr, S);

    // 5) causal softmax: fp32 Sc -> bf16 P
    softmax_kernel<<<dim3(S, B), blk, 0, stream>>>(Sc, P, S);

    // 6) out = P @ V (K-loop bounded at diagonal)
    gemm2<false, 2, 0><<<dim3(D / TN, S / TM, B), blk, 0, stream>>>(
        P, nullptr, (long)S * S, S, Vt, nullptr, (long)D * S, S, out, nullptr, nullptr,
        (long)S * D, D, S, nullptr, S);
}